// Round 1
// baseline (277.417 us; speedup 1.0000x reference)
//
#include <hip/hip_runtime.h>

// Problem constants (fixed by setup_inputs): N=64, L=256, C=384.
#define N_B   64
#define L_IN  256
#define C_DIM 384
#define C4_DIM (C_DIM / 4)

// Kernel A: per-batch inclusive cumsum of durations + searchsorted index table.
// One block per batch row; 256 threads == L_IN.
__global__ __launch_bounds__(256) void lr_idx_kernel(const int* __restrict__ dur,
                                                     int* __restrict__ idx_out,
                                                     int melmax) {
    __shared__ int csum[L_IN];
    const int n = blockIdx.x;
    const int tid = threadIdx.x;

    csum[tid] = dur[n * L_IN + tid];
    __syncthreads();
    // Hillis-Steele inclusive scan over 256 elements in LDS.
    #pragma unroll
    for (int off = 1; off < L_IN; off <<= 1) {
        int add = (tid >= off) ? csum[tid - off] : 0;
        __syncthreads();
        csum[tid] += add;
        __syncthreads();
    }
    const int total = csum[L_IN - 1];

    // For each output timestep t: idx = searchsorted(csum, t, side='right')
    // == count of csum entries <= t (lower-bound with <=). -1 marks invalid.
    for (int t = tid; t < melmax; t += 256) {
        int r = -1;
        if (t < total) {
            int lo = 0, hi = L_IN;
            #pragma unroll
            for (int s = 0; s < 8; ++s) {   // log2(256) iterations
                int mid = (lo + hi) >> 1;
                if (csum[mid] <= t) lo = mid + 1; else hi = mid;
            }
            r = (lo < (L_IN - 1)) ? lo : (L_IN - 1);
        }
        idx_out[n * melmax + t] = r;
    }
}

// Kernel B: gather rows of x into out, one float4 per thread. Coalesced stores;
// x row reads hit L2/L3 (x is 25 MB total, consecutive t mostly share idx).
__global__ __launch_bounds__(256) void lr_gather_kernel(const float4* __restrict__ x,
                                                        const int* __restrict__ idx,
                                                        float4* __restrict__ out,
                                                        int melmax, int total4) {
    int g = blockIdx.x * 256 + threadIdx.x;
    if (g >= total4) return;
    int c4   = g % C4_DIM;
    int rest = g / C4_DIM;
    int t = rest % melmax;
    int n = rest / melmax;

    int r = idx[n * melmax + t];
    float4 val;
    if (r < 0) {
        val = make_float4(0.f, 0.f, 0.f, 0.f);
    } else {
        val = x[(n * L_IN + r) * C4_DIM + c4];
    }
    out[g] = val;
}

// Kernel C: mel_pos = arange(1, melmax+1), written as float32.
__global__ __launch_bounds__(256) void lr_melpos_kernel(float* __restrict__ mp, int melmax) {
    int t = blockIdx.x * 256 + threadIdx.x;
    if (t < melmax) mp[t] = (float)(t + 1);
}

extern "C" void kernel_launch(void* const* d_in, const int* in_sizes, int n_in,
                              void* d_out, int out_size, void* d_ws, size_t ws_size,
                              hipStream_t stream) {
    const float* x  = (const float*)d_in[0];
    const int* dur  = (const int*)d_in[1];
    // d_in[2] (mel_max_length) is on device; derive it on host instead:
    // out_size = N*mel*C + mel = mel * (N*C + 1)
    const int melmax = out_size / (N_B * C_DIM + 1);

    int* idxbuf = (int*)d_ws;  // N_B * melmax ints (~600 KB)

    lr_idx_kernel<<<N_B, 256, 0, stream>>>(dur, idxbuf, melmax);

    const int total4 = N_B * melmax * C4_DIM;
    lr_gather_kernel<<<(total4 + 255) / 256, 256, 0, stream>>>(
        (const float4*)x, idxbuf, (float4*)d_out, melmax, total4);

    float* mp = (float*)d_out + (size_t)N_B * melmax * C_DIM;
    lr_melpos_kernel<<<(melmax + 255) / 256, 256, 0, stream>>>(mp, melmax);
}

// Round 2
// 276.332 us; speedup vs baseline: 1.0039x; 1.0039x over previous
//
#include <hip/hip_runtime.h>

// Problem constants (fixed by setup_inputs): N=64, L=256, C=384.
#define N_B   64
#define L_IN  256
#define C_DIM 384
#define C4    (C_DIM / 4)   // 96 float4 per row

// Kernel A: per-batch inclusive cumsum of durations + searchsorted index table,
// plus mel_pos (folded in, written by batch-0 block). One block per batch row.
__global__ __launch_bounds__(256) void lr_idx_kernel(const int* __restrict__ dur,
                                                     int* __restrict__ idx_out,
                                                     float* __restrict__ melpos,
                                                     int melmax) {
    __shared__ int csum[L_IN];
    const int n = blockIdx.x;
    const int tid = threadIdx.x;

    csum[tid] = dur[n * L_IN + tid];
    __syncthreads();
    // Hillis-Steele inclusive scan over 256 elements in LDS.
    #pragma unroll
    for (int off = 1; off < L_IN; off <<= 1) {
        int add = (tid >= off) ? csum[tid - off] : 0;
        __syncthreads();
        csum[tid] += add;
        __syncthreads();
    }
    const int total = csum[L_IN - 1];

    // idx = searchsorted(csum, t, side='right'), clamped to L-1; -1 marks invalid.
    for (int t = tid; t < melmax; t += 256) {
        int r = -1;
        if (t < total) {
            int lo = 0, hi = L_IN;
            #pragma unroll
            for (int s = 0; s < 8; ++s) {   // log2(256)
                int mid = (lo + hi) >> 1;
                if (csum[mid] <= t) lo = mid + 1; else hi = mid;
            }
            r = (lo < (L_IN - 1)) ? lo : (L_IN - 1);
        }
        idx_out[n * melmax + t] = r;
        if (n == 0) melpos[t] = (float)(t + 1);   // mel_pos = arange(1, melmax+1)
    }
}

// Kernel B: gather rows of x into out, one float4 per thread.
// XCD-locality: n = blockIdx.x % 64, so (assuming linear round-robin dispatch)
// XCD k only touches n ≡ k (mod 8) → 8 slices × 384 KB = 3 MB, fits 4 MiB L2.
// All div/mod by compile-time constants (96, 64) → mul-shift, no runtime div.
__global__ __launch_bounds__(256) void lr_gather_kernel(const float4* __restrict__ x,
                                                        const int* __restrict__ idx,
                                                        float4* __restrict__ out,
                                                        int melmax) {
    const int n     = blockIdx.x & 63;     // N_B = 64
    const int chunk = blockIdx.x >> 6;
    const int off   = chunk * 256 + (int)threadIdx.x;  // float4 offset within batch n
    const int row_f4 = melmax * C4;
    if (off >= row_f4) return;

    const int t  = off / C4;               // C4 = 96, compile-time → magic mul
    const int c4 = off - t * C4;

    const int r = idx[n * melmax + t];
    float4 v = make_float4(0.f, 0.f, 0.f, 0.f);
    if (r >= 0) v = x[(n * L_IN + r) * C4 + c4];
    out[(size_t)n * row_f4 + off] = v;
}

extern "C" void kernel_launch(void* const* d_in, const int* in_sizes, int n_in,
                              void* d_out, int out_size, void* d_ws, size_t ws_size,
                              hipStream_t stream) {
    const float* x  = (const float*)d_in[0];
    const int* dur  = (const int*)d_in[1];
    // d_in[2] (mel_max_length) is on device; derive on host:
    // out_size = N*mel*C + mel = mel * (N*C + 1)
    const int melmax = out_size / (N_B * C_DIM + 1);

    int* idxbuf = (int*)d_ws;  // N_B * melmax ints (~600 KB)
    float* mp   = (float*)d_out + (size_t)N_B * melmax * C_DIM;

    lr_idx_kernel<<<N_B, 256, 0, stream>>>(dur, idxbuf, mp, melmax);

    const int chunks_per_n = (melmax * C4 + 255) / 256;
    lr_gather_kernel<<<chunks_per_n * N_B, 256, 0, stream>>>(
        (const float4*)x, idxbuf, (float4*)d_out, melmax);
}

// Round 4
// 267.974 us; speedup vs baseline: 1.0352x; 1.0312x over previous
//
#include <hip/hip_runtime.h>

// Problem constants (fixed by setup_inputs): N=64, L=256, C=384.
#define N_B    64
#define L_IN   256
#define C_DIM  384
#define C4     (C_DIM / 4)      // 96 float4 per row
#define F4_PER_BLOCK 2048       // 8 iterations x 256 threads, 32 KB stored/block

// clang-native 4-float vector — accepted by __builtin_nontemporal_store
// (HIP's float4 is a struct wrapper and is rejected).
typedef float vfloat4 __attribute__((ext_vector_type(4)));

// Fused kernel: per-block re-derive the duration cumsum (1 KB, L2-hot),
// precompute r(t) for the block's t-range (<= 23 values), then stream
// F4_PER_BLOCK float4 of output with non-temporal stores (out is never
// re-read; keeps L2 free so x ~25 MB is fetched from HBM only once).
__global__ __launch_bounds__(256) void lr_fused_kernel(const vfloat4* __restrict__ x,
                                                       const int* __restrict__ dur,
                                                       vfloat4* __restrict__ out,
                                                       int melmax) {
    __shared__ int csum[L_IN];
    __shared__ int r_tab[32];   // r for t in [t0, t0+tcnt), tcnt <= 2048/96+2 = 23

    const int n      = blockIdx.x & 63;          // N_B = 64; keeps XCD spread over n
    const int bchunk = blockIdx.x >> 6;
    const int tid    = (int)threadIdx.x;
    const int row_f4 = melmax * C4;
    const int start  = bchunk * F4_PER_BLOCK;
    if (start >= row_f4) return;
    const int end    = min(start + F4_PER_BLOCK, row_f4);

    // 1) inclusive scan of durations for batch n (Hillis-Steele in LDS).
    csum[tid] = dur[n * L_IN + tid];
    __syncthreads();
    #pragma unroll
    for (int off = 1; off < L_IN; off <<= 1) {
        int add = (tid >= off) ? csum[tid - off] : 0;
        __syncthreads();
        csum[tid] += add;
        __syncthreads();
    }
    const int total = csum[L_IN - 1];

    // 2) r(t) for this block's t-range: searchsorted(csum, t, 'right'), clamp L-1.
    const int t0    = start / C4;
    const int tlast = (end - 1) / C4;
    const int tcnt  = tlast - t0 + 1;
    if (tid < tcnt) {
        const int t = t0 + tid;
        int r = -1;
        if (t < total) {
            int lo = 0, hi = L_IN;
            #pragma unroll
            for (int s = 0; s < 8; ++s) {   // log2(256)
                int mid = (lo + hi) >> 1;
                if (csum[mid] <= t) lo = mid + 1; else hi = mid;
            }
            r = (lo < (L_IN - 1)) ? lo : (L_IN - 1);
        }
        r_tab[tid] = r;
    }
    __syncthreads();

    // 3) stream the output slice: coalesced float4, non-temporal.
    const size_t obase = (size_t)n * row_f4;
    for (int off = start + tid; off < end; off += 256) {
        const int t  = off / C4;            // compile-time divisor -> mul/shift
        const int c4 = off - t * C4;
        const int r  = r_tab[t - t0];
        vfloat4 v = (vfloat4)0.f;
        if (r >= 0) v = x[(n * L_IN + r) * C4 + c4];
        __builtin_nontemporal_store(v, &out[obase + off]);
    }
}

// mel_pos = arange(1, melmax+1) as float32.
__global__ __launch_bounds__(256) void lr_melpos_kernel(float* __restrict__ mp, int melmax) {
    int t = blockIdx.x * 256 + threadIdx.x;
    if (t < melmax) mp[t] = (float)(t + 1);
}

extern "C" void kernel_launch(void* const* d_in, const int* in_sizes, int n_in,
                              void* d_out, int out_size, void* d_ws, size_t ws_size,
                              hipStream_t stream) {
    const float* x  = (const float*)d_in[0];
    const int* dur  = (const int*)d_in[1];
    // d_in[2] (mel_max_length) is device-resident; derive on host:
    // out_size = N*mel*C + mel = mel * (N*C + 1)
    const int melmax = out_size / (N_B * C_DIM + 1);

    const int row_f4 = melmax * C4;
    const int blocks_per_n = (row_f4 + F4_PER_BLOCK - 1) / F4_PER_BLOCK;

    lr_fused_kernel<<<blocks_per_n * N_B, 256, 0, stream>>>(
        (const vfloat4*)x, dur, (vfloat4*)d_out, melmax);

    float* mp = (float*)d_out + (size_t)N_B * melmax * C_DIM;
    lr_melpos_kernel<<<(melmax + 255) / 256, 256, 0, stream>>>(mp, melmax);
}

// Round 5
// 260.677 us; speedup vs baseline: 1.0642x; 1.0280x over previous
//
#include <hip/hip_runtime.h>

// Problem constants (fixed by setup_inputs): N=64, L=256, C=384.
#define N_B    64
#define L_IN   256
#define C_DIM  384
#define C4     (C_DIM / 4)      // 96 float4 per row
#define F4_PER_BLOCK 2048       // 8 iterations x 256 threads, 32 KB stored/block
#define ITERS  (F4_PER_BLOCK / 256)

// clang-native 4-float vector — accepted by __builtin_nontemporal_store
// (HIP's float4 is a struct wrapper and is rejected).
typedef float vfloat4 __attribute__((ext_vector_type(4)));

// Fused kernel: per-block re-derive the duration cumsum (1 KB, L2-hot),
// precompute r(t) for the block's t-range (<= 23 values), then stream
// F4_PER_BLOCK float4 of output with non-temporal stores. Full blocks take a
// compile-time-unrolled path (8 loads in flight, then 8 stores) for MLP.
__global__ __launch_bounds__(256) void lr_fused_kernel(const vfloat4* __restrict__ x,
                                                       const int* __restrict__ dur,
                                                       vfloat4* __restrict__ out,
                                                       float* __restrict__ melpos,
                                                       int melmax) {
    __shared__ int csum[L_IN];
    __shared__ int r_tab[32];   // r for t in [t0, t0+tcnt), tcnt <= 2048/96+2 = 23

    const int n      = blockIdx.x & 63;          // N_B=64; XCD k -> n%8==k, 3MB/L2
    const int bchunk = blockIdx.x >> 6;
    const int tid    = (int)threadIdx.x;
    const int row_f4 = melmax * C4;
    const int start  = bchunk * F4_PER_BLOCK;
    if (start >= row_f4) return;
    const bool full  = (start + F4_PER_BLOCK) <= row_f4;
    const int end    = full ? (start + F4_PER_BLOCK) : row_f4;

    // 1) inclusive scan of durations for batch n (Hillis-Steele in LDS).
    csum[tid] = dur[n * L_IN + tid];
    __syncthreads();
    #pragma unroll
    for (int off = 1; off < L_IN; off <<= 1) {
        int add = (tid >= off) ? csum[tid - off] : 0;
        __syncthreads();
        csum[tid] += add;
        __syncthreads();
    }
    const int total = csum[L_IN - 1];

    // 2) r(t) for this block's t-range: searchsorted(csum, t, 'right'), clamp L-1.
    const int t0    = start / C4;
    const int tlast = (end - 1) / C4;
    const int tcnt  = tlast - t0 + 1;
    if (tid < tcnt) {
        const int t = t0 + tid;
        int r = -1;
        if (t < total) {
            int lo = 0, hi = L_IN;
            #pragma unroll
            for (int s = 0; s < 8; ++s) {   // log2(256)
                int mid = (lo + hi) >> 1;
                if (csum[mid] <= t) lo = mid + 1; else hi = mid;
            }
            r = (lo < (L_IN - 1)) ? lo : (L_IN - 1);
        }
        r_tab[tid] = r;
        if (n == 0) melpos[t] = (float)(t + 1);   // mel_pos folded in (t covered 1-2x)
    }
    __syncthreads();

    // 3) stream the output slice: coalesced float4, non-temporal.
    const size_t obase = (size_t)n * row_f4;
    if (full) {
        vfloat4 v[ITERS];
        #pragma unroll
        for (int i = 0; i < ITERS; ++i) {
            const int off = start + tid + 256 * i;
            const int t   = off / C4;            // compile-time divisor -> mul/shift
            const int c4  = off - t * C4;
            const int r   = r_tab[t - t0];
            const int rc  = (r >= 0) ? r : 0;    // unconditional load; select after
            vfloat4 tmp = x[(n * L_IN + rc) * C4 + c4];
            v[i] = (r >= 0) ? tmp : (vfloat4)0.f;
        }
        #pragma unroll
        for (int i = 0; i < ITERS; ++i) {
            __builtin_nontemporal_store(v[i], &out[obase + start + tid + 256 * i]);
        }
    } else {
        for (int off = start + tid; off < end; off += 256) {
            const int t  = off / C4;
            const int c4 = off - t * C4;
            const int r  = r_tab[t - t0];
            vfloat4 v = (vfloat4)0.f;
            if (r >= 0) v = x[(n * L_IN + r) * C4 + c4];
            __builtin_nontemporal_store(v, &out[obase + off]);
        }
    }
}

extern "C" void kernel_launch(void* const* d_in, const int* in_sizes, int n_in,
                              void* d_out, int out_size, void* d_ws, size_t ws_size,
                              hipStream_t stream) {
    const float* x  = (const float*)d_in[0];
    const int* dur  = (const int*)d_in[1];
    // d_in[2] (mel_max_length) is device-resident; derive on host:
    // out_size = N*mel*C + mel = mel * (N*C + 1)
    const int melmax = out_size / (N_B * C_DIM + 1);

    const int row_f4 = melmax * C4;
    const int blocks_per_n = (row_f4 + F4_PER_BLOCK - 1) / F4_PER_BLOCK;
    float* mp = (float*)d_out + (size_t)N_B * melmax * C_DIM;

    lr_fused_kernel<<<blocks_per_n * N_B, 256, 0, stream>>>(
        (const vfloat4*)x, dur, (vfloat4*)d_out, mp, melmax);
}

// Round 6
// 257.333 us; speedup vs baseline: 1.0780x; 1.0130x over previous
//
#include <hip/hip_runtime.h>

// Problem constants (fixed by setup_inputs): N=64, L=256, C=384.
#define N_B    64
#define L_IN   256
#define C_DIM  384
#define C4     (C_DIM / 4)      // 96 float4 per row
#define F4_PER_BLOCK 2048       // 8 iterations x 256 threads, 32 KB stored/block
#define ITERS  (F4_PER_BLOCK / 256)
#define SPLIT  4                // t-range partitions in the idx kernel

// clang-native 4-float vector — accepted by __builtin_nontemporal_store.
typedef float vfloat4 __attribute__((ext_vector_type(4)));

// Kernel 1 (tiny): per-batch cumsum + searchsorted -> r table in ws, + melpos.
// 64 batches x SPLIT t-partitions = 256 blocks; scan is 1 KB, redundant scan
// per partition is cheap here (vs. redundant scan in all 7k gather blocks).
__global__ __launch_bounds__(256) void lr_idx_kernel(const int* __restrict__ dur,
                                                     int* __restrict__ idx_out,
                                                     float* __restrict__ melpos,
                                                     int melmax) {
    __shared__ int csum[L_IN];
    const int n    = blockIdx.x & 63;
    const int part = blockIdx.x >> 6;
    const int tid  = (int)threadIdx.x;

    csum[tid] = dur[n * L_IN + tid];
    __syncthreads();
    #pragma unroll
    for (int off = 1; off < L_IN; off <<= 1) {
        int add = (tid >= off) ? csum[tid - off] : 0;
        __syncthreads();
        csum[tid] += add;
        __syncthreads();
    }
    const int total = csum[L_IN - 1];

    const int per  = (melmax + SPLIT - 1) / SPLIT;
    const int tbeg = part * per;
    const int tend = min(tbeg + per, melmax);
    for (int t = tbeg + tid; t < tend; t += 256) {
        int r = -1;
        if (t < total) {
            int lo = 0, hi = L_IN;
            #pragma unroll
            for (int s = 0; s < 8; ++s) {   // log2(256)
                int mid = (lo + hi) >> 1;
                if (csum[mid] <= t) lo = mid + 1; else hi = mid;
            }
            r = (lo < (L_IN - 1)) ? lo : (L_IN - 1);
        }
        idx_out[n * melmax + t] = r;
        if (n == 0) melpos[t] = (float)(t + 1);   // mel_pos = arange(1, melmax+1)
    }
}

// Kernel 2 (stream): load <=23 r values for this chunk, then unrolled
// 8x load / 8x non-temporal store. Block ordering is chunk-major within an
// XCD: XCD k streams batch k, then k+8, ... so its live x working set is one
// batch row-set (~384 KB) and stays L2-resident under the write stream.
__global__ __launch_bounds__(256) void lr_gather_kernel(const vfloat4* __restrict__ x,
                                                        const int* __restrict__ idx,
                                                        vfloat4* __restrict__ out,
                                                        int melmax, int chunks_per_n) {
    __shared__ int r_tab[32];   // tcnt <= 2048/96 + 1 = 23

    const int j      = (int)blockIdx.x;
    const int xcd    = j & 7;               // dispatch round-robins XCDs
    const int s      = j >> 3;
    const int n      = xcd + 8 * (s / chunks_per_n);
    const int bchunk = s % chunks_per_n;
    const int tid    = (int)threadIdx.x;

    const int row_f4 = melmax * C4;
    const int start  = bchunk * F4_PER_BLOCK;
    if (start >= row_f4) return;
    const bool full  = (start + F4_PER_BLOCK) <= row_f4;
    const int end    = full ? (start + F4_PER_BLOCK) : row_f4;

    const int t0   = start / C4;
    const int tcnt = (end - 1) / C4 - t0 + 1;
    if (tid < tcnt) r_tab[tid] = idx[n * melmax + t0 + tid];
    __syncthreads();

    const size_t obase = (size_t)n * row_f4;
    if (full) {
        vfloat4 v[ITERS];
        #pragma unroll
        for (int i = 0; i < ITERS; ++i) {
            const int off = start + tid + 256 * i;
            const int t   = off / C4;            // const divisor -> mul/shift
            const int c4  = off - t * C4;
            const int r   = r_tab[t - t0];
            const int rc  = (r >= 0) ? r : 0;    // unconditional load; select after
            vfloat4 tmp = x[(n * L_IN + rc) * C4 + c4];
            v[i] = (r >= 0) ? tmp : (vfloat4)0.f;
        }
        #pragma unroll
        for (int i = 0; i < ITERS; ++i) {
            __builtin_nontemporal_store(v[i], &out[obase + start + tid + 256 * i]);
        }
    } else {
        for (int off = start + tid; off < end; off += 256) {
            const int t  = off / C4;
            const int c4 = off - t * C4;
            const int r  = r_tab[t - t0];
            vfloat4 v = (vfloat4)0.f;
            if (r >= 0) v = x[(n * L_IN + r) * C4 + c4];
            __builtin_nontemporal_store(v, &out[obase + off]);
        }
    }
}

extern "C" void kernel_launch(void* const* d_in, const int* in_sizes, int n_in,
                              void* d_out, int out_size, void* d_ws, size_t ws_size,
                              hipStream_t stream) {
    const float* x  = (const float*)d_in[0];
    const int* dur  = (const int*)d_in[1];
    // d_in[2] (mel_max_length) is device-resident; derive on host:
    // out_size = N*mel*C + mel = mel * (N*C + 1)
    const int melmax = out_size / (N_B * C_DIM + 1);

    int* idxbuf = (int*)d_ws;                                   // N_B*melmax ints
    float* mp   = (float*)d_out + (size_t)N_B * melmax * C_DIM; // mel_pos

    lr_idx_kernel<<<N_B * SPLIT, 256, 0, stream>>>(dur, idxbuf, mp, melmax);

    const int row_f4 = melmax * C4;
    const int chunks_per_n = (row_f4 + F4_PER_BLOCK - 1) / F4_PER_BLOCK;
    lr_gather_kernel<<<chunks_per_n * N_B, 256, 0, stream>>>(
        (const vfloat4*)x, idxbuf, (vfloat4*)d_out, melmax, chunks_per_n);
}